// Round 8
// baseline (484.608 us; speedup 1.0000x reference)
//
#include <hip/hip_runtime.h>
#include <hip/hip_bf16.h>
#include <math.h>

#define DI __device__ __forceinline__

typedef short s16x8 __attribute__((ext_vector_type(8)));
typedef unsigned short u16x8_t __attribute__((ext_vector_type(8)));
typedef float f32x4 __attribute__((ext_vector_type(4)));

static constexpr int T_TOK = 4096;   // B*S tokens
static constexpr int DM    = 1024;   // d_model
static constexpr int DFF   = 4096;   // d_ff
static constexpr int S_LEN = 2048;   // seq len
static constexpr int NB    = 2;      // batch
static constexpr int LDK   = 2048;   // fused q,k row stride

DI unsigned short f2bf(float f) {
    unsigned int u = __builtin_bit_cast(unsigned int, f);
    u += 0x7fffu + ((u >> 16) & 1u);
    return (unsigned short)(u >> 16);
}

DI unsigned pack_bf2(float a, float b) {
    unsigned ua = __builtin_bit_cast(unsigned, a) + 0x8000u;
    unsigned ub = __builtin_bit_cast(unsigned, b) + 0x8000u;
    return __builtin_amdgcn_perm(ub, ua, 0x07060302u);
}

DI float gelu_f(float x) {
    return 0.5f * x * (1.0f + erff(x * 0.70710678118654752440f));
}

DI int swz(int r) { return (r ^ (r >> 3)) & 7; }

DI void gload_lds16(const void* g, void* l) {
    __builtin_amdgcn_global_load_lds((const unsigned int*)g, (unsigned int*)l, 16, 0, 0);
}

// ---------------- transpose + fp32->bf16 convert: in[K][N] -> out[N][K] ----------------
__global__ __launch_bounds__(256) void tcvt_kernel(const float* __restrict__ in,
                                                   unsigned short* __restrict__ out,
                                                   int K, int N) {
    __shared__ float tile[32][33];
    const int tx = threadIdx.x & 31, ty = threadIdx.x >> 5;
    const int k0 = blockIdx.y * 32, n0 = blockIdx.x * 32;
#pragma unroll
    for (int i = 0; i < 4; ++i) {
        int k = ty + i * 8;
        tile[k][tx] = in[(size_t)(k0 + k) * N + n0 + tx];
    }
    __syncthreads();
#pragma unroll
    for (int i = 0; i < 4; ++i) {
        int n = ty + i * 8;
        out[(size_t)(n0 + n) * K + k0 + tx] = f2bf(tile[tx][n]);
    }
}

// ---------------- LayerNorm (fp32 in, bf16 out) ----------------
__global__ __launch_bounds__(256) void ln_kernel(const float* __restrict__ x,
                                                 const float* __restrict__ g,
                                                 const float* __restrict__ b,
                                                 unsigned short* __restrict__ out) {
    int row = blockIdx.x;
    int t = threadIdx.x;
    const float4 v = reinterpret_cast<const float4*>(x + (size_t)row * DM)[t];
    float s = v.x + v.y + v.z + v.w;
    float s2 = v.x * v.x + v.y * v.y + v.z * v.z + v.w * v.w;
#pragma unroll
    for (int m = 1; m < 64; m <<= 1) { s += __shfl_xor(s, m, 64); s2 += __shfl_xor(s2, m, 64); }
    __shared__ float red[8];
    int w = t >> 6;
    if ((t & 63) == 0) { red[w] = s; red[4 + w] = s2; }
    __syncthreads();
    s = red[0] + red[1] + red[2] + red[3];
    s2 = red[4] + red[5] + red[6] + red[7];
    float mu = s * (1.0f / DM);
    float var = s2 * (1.0f / DM) - mu * mu;
    float rs = rsqrtf(var + 1e-5f);
    float4 gv = reinterpret_cast<const float4*>(g)[t];
    float4 bv = reinterpret_cast<const float4*>(b)[t];
    ushort4 ov = make_ushort4(f2bf((v.x - mu) * rs * gv.x + bv.x),
                              f2bf((v.y - mu) * rs * gv.y + bv.y),
                              f2bf((v.z - mu) * rs * gv.z + bv.z),
                              f2bf((v.w - mu) * rs * gv.w + bv.w));
    reinterpret_cast<ushort4*>(out + (size_t)row * DM)[t] = ov;
}

// ============ 256x256 8-phase GEMM: C = A[M,K] @ Bt[N,K]^T, BK=64, 512 thr ============
// 8 waves (wr=w>>2, wc=w&3), per-wave out 128x64. LDS [buf][op][row'][64] row-reordered:
//   A: row' = qm*128 + wr*64 + lo  <->  m = m0 + wr*128 + qm*64 + lo
//   B: row' = qn*128 + wc*32 + lo5 <->  n = n0 + wc*64 + qn*32 + lo5
// so each 128-row' "group" (A:qm, B:qn half) is a contiguous 16KB staging unit that
// frees mid-iteration. Phases interleave tiles: ph p = quad(qm=(p>>1)&1, qn=p>>2) of
// T(p&1). Stage slots / end-of-phase counted waits derived by ledger (see comments).
// Reads XOR-swizzle 16B slots by row' (2 lanes/slot = conflict-free); staging sources
// are pre-swizzled so gload_lds dest stays linear.
// EPI: 2 = gelu(+bias) bf16 out; 4 = qkv (Q,K->Cv stride 2048, Q*0.125; V^T->Cv2)
template <int EPI>
__global__ __launch_bounds__(512, 1) void gemm256_kernel(
    const unsigned short* __restrict__ A,
    const unsigned short* __restrict__ Bt,
    const float* __restrict__ bias,
    void* __restrict__ Cv, void* __restrict__ Cv2,
    int M, int N, int K, int nbx) {
    __shared__ unsigned short lds[2][2][256][64];
    const int t = threadIdx.x, lane = t & 63, w = t >> 6;
    const int wr = w >> 2, wc = w & 3;
    const int c = lane & 15, g = lane >> 4;

    const int nwg = gridDim.x;
    const int bid = blockIdx.x;
    const int sbid = (bid & 7) * (nwg >> 3) + (bid >> 3);
    const int bx = sbid % nbx, by = sbid / nbx;
    const int m0 = by * 256, n0 = bx * 256;

    // staging source byte-offsets [group][chunk]; dest is linear, src pre-swizzled
    const int lrow = w * 8 + (lane >> 3);
    const int lslot = lane & 7;
    size_t aoff[2][2], boff[2][2];
#pragma unroll
    for (int gq = 0; gq < 2; ++gq)
#pragma unroll
        for (int ch = 0; ch < 2; ++ch) {
            int rowp = gq * 128 + ch * 64 + lrow;
            int slot = lslot ^ swz(rowp);
            int am = m0 + ch * 128 + gq * 64 + lrow;
            aoff[gq][ch] = (size_t)am * K * 2 + (size_t)slot * 16;
            int inb = ch * 64 + lrow;
            int bn = n0 + (inb >> 5) * 64 + gq * 32 + (inb & 31);
            boff[gq][ch] = (size_t)bn * K * 2 + (size_t)slot * 16;
        }

    auto stgA = [&](int buf, int gq, int kt) {
#pragma unroll
        for (int ch = 0; ch < 2; ++ch)
            gload_lds16((const char*)A + aoff[gq][ch] + (size_t)kt * 128,
                        &lds[buf][0][gq * 128 + ch * 64 + w * 8][0]);
    };
    auto stgB = [&](int buf, int gq, int kt) {
#pragma unroll
        for (int ch = 0; ch < 2; ++ch)
            gload_lds16((const char*)Bt + boff[gq][ch] + (size_t)kt * 128,
                        &lds[buf][1][gq * 128 + ch * 64 + w * 8][0]);
    };

    f32x4 acc[8][4] = {};
    struct Frags { s16x8 af[4][2]; s16x8 bf[2][2]; };

    auto ldq = [&](int buf, int qm, int qn, Frags& f) {
        const char* La = (const char*)&lds[buf][0][0][0];
        const char* Lb = (const char*)&lds[buf][1][0][0];
#pragma unroll
        for (int mi = 0; mi < 4; ++mi) {
            int row = qm * 128 + wr * 64 + mi * 16 + c;
            int sw = swz(row);
#pragma unroll
            for (int k = 0; k < 2; ++k)
                f.af[mi][k] = *(const s16x8*)(La + row * 128 + (((k << 2) + g) ^ sw) * 16);
        }
#pragma unroll
        for (int ni = 0; ni < 2; ++ni) {
            int row = qn * 128 + wc * 32 + ni * 16 + c;
            int sw = swz(row);
#pragma unroll
            for (int k = 0; k < 2; ++k)
                f.bf[ni][k] = *(const s16x8*)(Lb + row * 128 + (((k << 2) + g) ^ sw) * 16);
        }
    };
    auto mmq = [&](int qm, int qn, const Frags& f) {
        __builtin_amdgcn_s_setprio(1);
#pragma unroll
        for (int mi = 0; mi < 4; ++mi)
#pragma unroll
            for (int ni = 0; ni < 2; ++ni)
#pragma unroll
                for (int k = 0; k < 2; ++k)
                    acc[qm * 4 + mi][qn * 2 + ni] = __builtin_amdgcn_mfma_f32_16x16x32_bf16(
                        f.af[mi][k], f.bf[ni][k], acc[qm * 4 + mi][qn * 2 + ni], 0, 0, 0);
        __builtin_amdgcn_s_setprio(0);
    };

#define BAR() __builtin_amdgcn_s_barrier()
#define VM(N) asm volatile("s_waitcnt vmcnt(" #N ")" ::: "memory")

    // prologue: tile0 complete -> buf0; tile1 groups (B:h0, A:m0) -> buf1; full drain.
    stgB(0, 0, 0); stgA(0, 0, 0); stgB(0, 1, 0); stgA(0, 1, 0);
    stgB(1, 0, 1); stgA(1, 0, 1);
    VM(0); BAR();

    const int NI = K >> 7;   // iterations of 2 K-tiles (BK=64)
    for (int it = 0; it < NI; ++it) {
        const bool last = (it == NI - 1);
        const int T0k = 2 * it, T1k = 2 * it + 1;
        Frags f;
        // ph0: T0 quad(m0,n0); stage Am1(T1)->buf1
        ldq(0, 0, 0, f); stgA(1, 1, T1k); BAR(); mmq(0, 0, f); VM(6); BAR();
        // ph1: T1 quad(m0,n0); stage Bh1(T1)->buf1
        ldq(1, 0, 0, f); stgB(1, 1, T1k); BAR(); mmq(0, 0, f); VM(6); BAR();
        // ph2: T0 quad(m1,n0)
        ldq(0, 1, 0, f); BAR(); mmq(1, 0, f);
        if (last) { VM(0); } else { VM(2); }
        BAR();
        // ph3: T1 quad(m1,n0); stage Bh0(T0+2)->buf0
        ldq(1, 1, 0, f); if (!last) stgB(0, 0, T0k + 2); BAR(); mmq(1, 0, f); VM(6); BAR();
        // ph4: T0 quad(m0,n1); stage Bh0(T1+2)->buf1
        ldq(0, 0, 1, f); if (!last) stgB(1, 0, T1k + 2); BAR(); mmq(0, 1, f);
        if (last) { VM(0); } else { VM(4); }
        BAR();
        // ph5: T1 quad(m0,n1); stage Am0(T0+2)->buf0
        ldq(1, 0, 1, f); if (!last) stgA(0, 0, T0k + 2); BAR(); mmq(0, 1, f); BAR();
        // ph6: T0 quad(m1,n1); stage Am0(T1+2)->buf1
        ldq(0, 1, 1, f); if (!last) stgA(1, 0, T1k + 2); BAR(); mmq(1, 1, f); BAR();
        // ph7: T1 quad(m1,n1); stage Am1(T0+2)+Bh1(T0+2)->buf0
        ldq(1, 1, 1, f);
        if (!last) { stgA(0, 1, T0k + 2); stgB(0, 1, T0k + 2); }
        BAR(); mmq(1, 1, f); VM(6); BAR();
    }
#undef BAR
#undef VM

    // epilogue
#pragma unroll
    for (int mi = 0; mi < 8; ++mi) {
        const int rowb = m0 + wr * 128 + (mi >> 2) * 64 + (mi & 3) * 16 + g * 4;
#pragma unroll
        for (int ni = 0; ni < 4; ++ni) {
            const int col = n0 + wc * 64 + (ni >> 1) * 32 + (ni & 1) * 16 + c;
#pragma unroll
            for (int j = 0; j < 4; ++j) {
                const int row = rowb + j;
                float v = acc[mi][ni][j];
                if constexpr (EPI == 2) {
                    v = gelu_f(v + bias[col]);
                    ((unsigned short*)Cv)[(size_t)row * N + col] = f2bf(v);
                } else {  // EPI == 4
                    if (col < 2048) {
                        float vv = (col < 1024) ? v * 0.125f : v;
                        ((unsigned short*)Cv)[(size_t)row * LDK + col] = f2bf(vv);
                    } else {
                        ((unsigned short*)Cv2)[(size_t)(col - 2048) * T_TOK + row] = f2bf(v);
                    }
                }
            }
        }
    }
}

// ---------------- 128-tile GEMM (depth-2 pipeline) for N=1024 outputs ----------------
// EPI: 1 = +resid (f32 out), 3 = +bias+resid (f32 out)
template <int EPI, int BN>
__global__ __launch_bounds__(256) void gemm_kernel(const unsigned short* __restrict__ A,
                                                   const unsigned short* __restrict__ Bt,
                                                   const float* __restrict__ bias,
                                                   const float* __restrict__ resid,
                                                   void* __restrict__ Cv, void* __restrict__ Cv2,
                                                   int M, int N, int K) {
    constexpr int NN = BN / 32;
    constexpr int BCH = BN / 64;
    __shared__ unsigned short Asm[3][128][32];
    __shared__ unsigned short Bsm[3][BN][32];
    const int t = threadIdx.x, lane = t & 63, w = t >> 6;
    const int wr = w >> 1, wc = w & 1;
    const int m0 = blockIdx.y * 128, n0 = blockIdx.x * BN;
    const int c = lane & 15, g = lane >> 4;
    const int srow = lane >> 2, scol = (lane & 3) * 8;

    f32x4 acc[4][NN] = {};
    const unsigned short* Ab = A + (size_t)m0 * K;
    const unsigned short* Bb = Bt + (size_t)n0 * K;

    auto stage = [&](int buf, int k0) {
#pragma unroll
        for (int cc = 0; cc < 2; ++cc) {
            int ch = 2 * w + cc;
            int r = ch * 16 + srow;
            gload_lds16(Ab + (size_t)r * K + k0 + scol, &Asm[buf][ch * 16][0]);
        }
#pragma unroll
        for (int cc = 0; cc < BCH; ++cc) {
            int ch = BCH * w + cc;
            int r = ch * 16 + srow;
            gload_lds16(Bb + (size_t)r * K + k0 + scol, &Bsm[buf][ch * 16][0]);
        }
    };

    auto compute = [&](int buf) {
        s16x8 af[4], bf[NN];
#pragma unroll
        for (int i = 0; i < 4; ++i)
            af[i] = *reinterpret_cast<const s16x8*>(&Asm[buf][wr * 64 + i * 16 + c][g * 8]);
#pragma unroll
        for (int n = 0; n < NN; ++n)
            bf[n] = *reinterpret_cast<const s16x8*>(&Bsm[buf][wc * (BN / 2) + n * 16 + c][g * 8]);
#pragma unroll
        for (int i = 0; i < 4; ++i)
#pragma unroll
            for (int n = 0; n < NN; ++n)
                acc[i][n] = __builtin_amdgcn_mfma_f32_16x16x32_bf16(af[i], bf[n], acc[i][n], 0, 0, 0);
    };

    const int NK = K >> 5;
    stage(0, 0);
    stage(1, 32);
    int buf = 0;
    for (int i = 0; i < NK - 1; ++i) {
        if constexpr (BCH == 2) asm volatile("s_waitcnt vmcnt(4)" ::: "memory");
        else                    asm volatile("s_waitcnt vmcnt(3)" ::: "memory");
        __builtin_amdgcn_s_barrier();
        compute(buf);
        if (i + 2 < NK) {
            int nb = buf + 2; if (nb >= 3) nb -= 3;
            stage(nb, (i + 2) << 5);
        }
        ++buf; if (buf == 3) buf = 0;
    }
    asm volatile("s_waitcnt vmcnt(0)" ::: "memory");
    __builtin_amdgcn_s_barrier();
    compute(buf);

    const int crow = g * 4;
#pragma unroll
    for (int i = 0; i < 4; ++i) {
#pragma unroll
        for (int n = 0; n < NN; ++n) {
            const int col = n0 + wc * (BN / 2) + n * 16 + c;
#pragma unroll
            for (int j = 0; j < 4; ++j) {
                const int row = m0 + wr * 64 + i * 16 + crow + j;
                float v = acc[i][n][j];
                if constexpr (EPI == 3) {
                    v = v + bias[col] + resid[(size_t)row * N + col];
                    ((float*)Cv)[(size_t)row * N + col] = v;
                } else {  // EPI == 1
                    v = v + resid[(size_t)row * N + col];
                    ((float*)Cv)[(size_t)row * N + col] = v;
                }
            }
        }
    }
}

// ---------------- Flash attention (fixed-max softmax, swapped QK^T) ----------------
__global__ __launch_bounds__(256) void attn_kernel(const unsigned short* __restrict__ QK,
                                                   const unsigned short* __restrict__ Vt,
                                                   const unsigned char* __restrict__ mask,
                                                   unsigned short* __restrict__ O) {
    const int qt = blockIdx.x, h = blockIdx.y, b = blockIdx.z;
    const int t = threadIdx.x, lane = t & 63, w = t >> 6;
    const int c = lane & 15, g = lane >> 4;
    const int crow = g * 4;
    const int qb0 = qt * 64;
    const int qw = qb0 + w * 16;
    const int swzc16 = swz(c) << 4;

    __shared__ unsigned short Ksm[2][64][64];
    __shared__ unsigned short Vsm[2][64][64];
    __shared__ unsigned short Psm[4][16][64];
    __shared__ unsigned char Msm[64][64];

    s16x8 qf[2];
    {
        const unsigned short* qp = QK + (size_t)(b * S_LEN + qw + c) * LDK + h * 64 + g * 8;
        qf[0] = *reinterpret_cast<const s16x8*>(qp);
        qf[1] = *reinterpret_cast<const s16x8*>(qp + 32);
    }

    float lsum = 0.f;
    f32x4 oacc[4] = {};

    const int vtok = t >> 2;
    const int vd0 = (t & 3) * 16;
    const unsigned char* mcol = mask + (size_t)b * S_LEN * S_LEN + (size_t)(qb0 + vtok) * S_LEN + vd0;
    const unsigned short* kg = QK + 1024;
    const int srow8 = lane >> 3, sslot = lane & 7;

    auto stage = [&](int buf, int kt) {
#pragma unroll
        for (int cc = 0; cc < 2; ++cc) {
            int ch = 2 * w + cc;
            int r = ch * 8 + srow8;
            int slot = sslot ^ swz(r);
            gload_lds16(kg + (size_t)(b * S_LEN + kt + r) * LDK + h * 64 + slot * 8,
                        &Ksm[buf][ch * 8][0]);
            gload_lds16(Vt + (size_t)(h * 64 + r) * T_TOK + b * S_LEN + kt + slot * 8,
                        &Vsm[buf][ch * 8][0]);
        }
    };

    stage(0, 0);
    uint4 mv0 = *reinterpret_cast<const uint4*>(mcol);
    asm volatile("s_waitcnt vmcnt(0)" ::: "memory");
    int anym = __syncthreads_or((mv0.x | mv0.y | mv0.z | mv0.w) != 0);
    if (anym) {
        *reinterpret_cast<uint4*>(&Msm[vtok][vd0]) = mv0;
        __syncthreads();
    }

    constexpr int NT = S_LEN / 64;
    for (int it = 0; it < NT; ++it) {
        const int cur = it & 1;
        uint4 mv = {0u, 0u, 0u, 0u};
        if (it < NT - 1) {
            stage(cur ^ 1, (it + 1) * 64);
            mv = *reinterpret_cast<const uint4*>(mcol + (it + 1) * 64);
        }

        f32x4 s[4] = {};
#pragma unroll
        for (int kh = 0; kh < 2; ++kh) {
#pragma unroll
            for (int kb = 0; kb < 4; ++kb) {
                int key = kb * 16 + c;
                int byte = key * 128 + (((kh * 4 + g) ^ swz(key)) << 4);
                s16x8 kf = *(const s16x8*)((const char*)&Ksm[cur][0][0] + byte);
                s[kb] = __builtin_amdgcn_mfma_f32_16x16x32_bf16(kf, qf[kh], s[kb], 0, 0, 0);
            }
        }
        if (anym) {
#pragma unroll
            for (int kb = 0; kb < 4; ++kb)
#pragma unroll
                for (int j = 0; j < 4; ++j)
                    if (Msm[w * 16 + c][kb * 16 + crow + j]) s[kb][j] = -1e9f;
        }

#pragma unroll
        for (int kb = 0; kb < 4; ++kb) {
            float p0 = __expf(s[kb][0]);
            float p1 = __expf(s[kb][1]);
            float p2 = __expf(s[kb][2]);
            float p3 = __expf(s[kb][3]);
            lsum += (p0 + p1) + (p2 + p3);
            uint2 pk = make_uint2(pack_bf2(p0, p1), pack_bf2(p2, p3));
            int byte = c * 128 + ((kb * 32 + g * 8) ^ swzc16);
            *(uint2*)((char*)&Psm[w][0][0] + byte) = pk;
        }

#pragma unroll
        for (int kh = 0; kh < 2; ++kh) {
            int pbyte = c * 128 + ((kh * 64 + g * 16) ^ swzc16);
            s16x8 pf = *(const s16x8*)((const char*)&Psm[w][0][0] + pbyte);
#pragma unroll
            for (int nb = 0; nb < 4; ++nb) {
                int d = nb * 16 + c;
                int byte = d * 128 + (((kh * 4 + g) ^ swz(d)) << 4);
                s16x8 vf = *(const s16x8*)((const char*)&Vsm[cur][0][0] + byte);
                oacc[nb] = __builtin_amdgcn_mfma_f32_16x16x32_bf16(pf, vf, oacc[nb], 0, 0, 0);
            }
        }

        asm volatile("s_waitcnt vmcnt(0)" ::: "memory");
        int nxt = __syncthreads_or((mv.x | mv.y | mv.z | mv.w) != 0);
        if (nxt) {
            *reinterpret_cast<uint4*>(&Msm[vtok][vd0]) = mv;
            __syncthreads();
        }
        anym = nxt;
    }

    lsum += __shfl_xor(lsum, 16);
    lsum += __shfl_xor(lsum, 32);
    float inv[4];
#pragma unroll
    for (int j = 0; j < 4; ++j) {
        float lq = __shfl(lsum, crow + j);
        inv[j] = lq > 0.f ? 1.0f / lq : 0.f;
    }
#pragma unroll
    for (int nb = 0; nb < 4; ++nb) {
#pragma unroll
        for (int j = 0; j < 4; ++j) {
            const size_t oo = (size_t)(b * S_LEN + qw + crow + j) * DM + h * 64 + nb * 16 + c;
            O[oo] = f2bf(oacc[nb][j] * inv[j]);
        }
    }
}

// ---------------- launch ----------------
extern "C" void kernel_launch(void* const* d_in, const int* in_sizes, int n_in,
                              void* d_out, int out_size, void* d_ws, size_t ws_size,
                              hipStream_t stream) {
    (void)in_sizes; (void)n_in; (void)out_size; (void)ws_size;
    const float* x   = (const float*)d_in[0];
    const unsigned char* mask = (const unsigned char*)d_in[1];
    const float* WQ  = (const float*)d_in[2];
    const float* WK  = (const float*)d_in[3];
    const float* WV  = (const float*)d_in[4];
    const float* WO  = (const float*)d_in[5];
    const float* F1W = (const float*)d_in[6];
    const float* F1B = (const float*)d_in[7];
    const float* F2W = (const float*)d_in[8];
    const float* F2B = (const float*)d_in[9];
    const float* L1G = (const float*)d_in[10];
    const float* L1B = (const float*)d_in[11];
    const float* L2G = (const float*)d_in[12];
    const float* L2B = (const float*)d_in[13];
    float* out = (float*)d_out;

    char* ws = (char*)d_ws;
    size_t off = 0;
    auto alloc = [&](size_t bytes) -> void* {
        void* p = ws + off;
        off += (bytes + 255) & ~(size_t)255;
        return p;
    };
    unsigned short* h1    = (unsigned short*)alloc((size_t)T_TOK * DM * 2);
    unsigned short* qk    = (unsigned short*)alloc((size_t)T_TOK * LDK * 2);
    unsigned short* vt    = (unsigned short*)alloc((size_t)DM * T_TOK * 2);
    unsigned short* ctx   = (unsigned short*)alloc((size_t)T_TOK * DM * 2);
    float*          x2    = (float*)alloc((size_t)T_TOK * DM * 4);
    unsigned short* h2    = (unsigned short*)alloc((size_t)T_TOK * DM * 2);
    unsigned short* h3    = (unsigned short*)alloc((size_t)T_TOK * DFF * 2);
    unsigned short* WQKVt = (unsigned short*)alloc((size_t)3 * DM * DM * 2);
    unsigned short* WOt   = (unsigned short*)alloc((size_t)DM * DM * 2);
    unsigned short* F1Wt  = (unsigned short*)alloc((size_t)DFF * DM * 2);
    unsigned short* F2Wt  = (unsigned short*)alloc((size_t)DM * DFF * 2);

    dim3 t32(DM / 32, DM / 32);
    tcvt_kernel<<<t32, 256, 0, stream>>>(WQ, WQKVt, DM, DM);
    tcvt_kernel<<<t32, 256, 0, stream>>>(WK, WQKVt + (size_t)DM * DM, DM, DM);
    tcvt_kernel<<<t32, 256, 0, stream>>>(WV, WQKVt + (size_t)2 * DM * DM, DM, DM);
    tcvt_kernel<<<t32, 256, 0, stream>>>(WO, WOt, DM, DM);
    tcvt_kernel<<<dim3(DFF / 32, DM / 32), 256, 0, stream>>>(F1W, F1Wt, DM, DFF);
    tcvt_kernel<<<dim3(DM / 32, DFF / 32), 256, 0, stream>>>(F2W, F2Wt, DFF, DM);

    ln_kernel<<<T_TOK, 256, 0, stream>>>(x, L1G, L1B, h1);

    gemm256_kernel<4><<<(3072 / 256) * (T_TOK / 256), 512, 0, stream>>>(
        h1, WQKVt, nullptr, qk, vt, T_TOK, 3072, DM, 3072 / 256);

    attn_kernel<<<dim3(S_LEN / 64, 16, NB), 256, 0, stream>>>(qk, vt, mask, ctx);

    gemm_kernel<1, 64><<<dim3(DM / 64, T_TOK / 128), 256, 0, stream>>>(
        ctx, WOt, nullptr, x, x2, nullptr, T_TOK, DM, DM);

    ln_kernel<<<T_TOK, 256, 0, stream>>>(x2, L2G, L2B, h2);

    gemm256_kernel<2><<<(DFF / 256) * (T_TOK / 256), 512, 0, stream>>>(
        h2, F1Wt, F1B, h3, nullptr, T_TOK, DFF, DM, DFF / 256);

    gemm_kernel<3, 64><<<dim3(DM / 64, T_TOK / 128), 256, 0, stream>>>(
        h3, F2Wt, F2B, x2, out, nullptr, T_TOK, DM, DFF);
}

// Round 9
// 442.500 us; speedup vs baseline: 1.0952x; 1.0952x over previous
//
#include <hip/hip_runtime.h>
#include <hip/hip_bf16.h>
#include <math.h>

#define DI __device__ __forceinline__

typedef short s16x8 __attribute__((ext_vector_type(8)));
typedef unsigned short u16x8_t __attribute__((ext_vector_type(8)));
typedef float f32x4 __attribute__((ext_vector_type(4)));

static constexpr int T_TOK = 4096;   // B*S tokens
static constexpr int DM    = 1024;   // d_model
static constexpr int DFF   = 4096;   // d_ff
static constexpr int S_LEN = 2048;   // seq len
static constexpr int NB    = 2;      // batch
static constexpr int LDK   = 2048;   // fused q,k row stride

DI unsigned short f2bf(float f) {
    unsigned int u = __builtin_bit_cast(unsigned int, f);
    u += 0x7fffu + ((u >> 16) & 1u);
    return (unsigned short)(u >> 16);
}

DI unsigned pack_bf2(float a, float b) {
    unsigned ua = __builtin_bit_cast(unsigned, a) + 0x8000u;
    unsigned ub = __builtin_bit_cast(unsigned, b) + 0x8000u;
    return __builtin_amdgcn_perm(ub, ua, 0x07060302u);
}

DI float gelu_f(float x) {
    return 0.5f * x * (1.0f + erff(x * 0.70710678118654752440f));
}

DI int swz(int r) { return (r ^ (r >> 3)) & 7; }

DI void gload_lds16(const void* g, void* l) {
    __builtin_amdgcn_global_load_lds((const unsigned int*)g, (unsigned int*)l, 16, 0, 0);
}

// ---------------- transpose + fp32->bf16 convert: in[K][N] -> out[N][K] ----------------
__global__ __launch_bounds__(256) void tcvt_kernel(const float* __restrict__ in,
                                                   unsigned short* __restrict__ out,
                                                   int K, int N) {
    __shared__ float tile[32][33];
    const int tx = threadIdx.x & 31, ty = threadIdx.x >> 5;
    const int k0 = blockIdx.y * 32, n0 = blockIdx.x * 32;
#pragma unroll
    for (int i = 0; i < 4; ++i) {
        int k = ty + i * 8;
        tile[k][tx] = in[(size_t)(k0 + k) * N + n0 + tx];
    }
    __syncthreads();
#pragma unroll
    for (int i = 0; i < 4; ++i) {
        int n = ty + i * 8;
        out[(size_t)(n0 + n) * K + k0 + tx] = f2bf(tile[tx][n]);
    }
}

// ---------------- LayerNorm (fp32 in, bf16 out) ----------------
__global__ __launch_bounds__(256) void ln_kernel(const float* __restrict__ x,
                                                 const float* __restrict__ g,
                                                 const float* __restrict__ b,
                                                 unsigned short* __restrict__ out) {
    int row = blockIdx.x;
    int t = threadIdx.x;
    const float4 v = reinterpret_cast<const float4*>(x + (size_t)row * DM)[t];
    float s = v.x + v.y + v.z + v.w;
    float s2 = v.x * v.x + v.y * v.y + v.z * v.z + v.w * v.w;
#pragma unroll
    for (int m = 1; m < 64; m <<= 1) { s += __shfl_xor(s, m, 64); s2 += __shfl_xor(s2, m, 64); }
    __shared__ float red[8];
    int w = t >> 6;
    if ((t & 63) == 0) { red[w] = s; red[4 + w] = s2; }
    __syncthreads();
    s = red[0] + red[1] + red[2] + red[3];
    s2 = red[4] + red[5] + red[6] + red[7];
    float mu = s * (1.0f / DM);
    float var = s2 * (1.0f / DM) - mu * mu;
    float rs = rsqrtf(var + 1e-5f);
    float4 gv = reinterpret_cast<const float4*>(g)[t];
    float4 bv = reinterpret_cast<const float4*>(b)[t];
    ushort4 ov = make_ushort4(f2bf((v.x - mu) * rs * gv.x + bv.x),
                              f2bf((v.y - mu) * rs * gv.y + bv.y),
                              f2bf((v.z - mu) * rs * gv.z + bv.z),
                              f2bf((v.w - mu) * rs * gv.w + bv.w));
    reinterpret_cast<ushort4*>(out + (size_t)row * DM)[t] = ov;
}

// ---------------- GEMM: C[M,N] = A[M,K](bf16) @ Bt[N,K](bf16)^T + epilogue ----------------
// Depth-2 prefetch pipeline: 3 LDS buffers, counted vmcnt (never 0 in main loop).
// vmcnt(N): N = loads-per-stage-per-thread = 2 + BCH (BN=128 -> 4, BN=64 -> 3).
// EPI: 1 = +resid (f32 out), 2 = gelu(+bias) (bf16 out), 3 = +bias+resid (f32 out),
//      4 = qkv (Q,K bf16 -> Cv stride 2048, Q scaled 0.125*log2e; V bf16 transposed -> Cv2)
template <int EPI, int BN>
__global__ __launch_bounds__(256) void gemm_kernel(const unsigned short* __restrict__ A,
                                                   const unsigned short* __restrict__ Bt,
                                                   const float* __restrict__ bias,
                                                   const float* __restrict__ resid,
                                                   void* __restrict__ Cv, void* __restrict__ Cv2,
                                                   int M, int N, int K) {
    constexpr int NN = BN / 32;
    constexpr int BCH = BN / 64;
    __shared__ unsigned short Asm[3][128][32];
    __shared__ unsigned short Bsm[3][BN][32];
    const int t = threadIdx.x, lane = t & 63, w = t >> 6;
    const int wr = w >> 1, wc = w & 1;
    const int m0 = blockIdx.y * 128, n0 = blockIdx.x * BN;
    const int c = lane & 15, g = lane >> 4;
    const int srow = lane >> 2, scol = (lane & 3) * 8;

    f32x4 acc[4][NN] = {};
    const unsigned short* Ab = A + (size_t)m0 * K;
    const unsigned short* Bb = Bt + (size_t)n0 * K;

    auto stage = [&](int buf, int k0) {
#pragma unroll
        for (int cc = 0; cc < 2; ++cc) {
            int ch = 2 * w + cc;
            int r = ch * 16 + srow;
            gload_lds16(Ab + (size_t)r * K + k0 + scol, &Asm[buf][ch * 16][0]);
        }
#pragma unroll
        for (int cc = 0; cc < BCH; ++cc) {
            int ch = BCH * w + cc;
            int r = ch * 16 + srow;
            gload_lds16(Bb + (size_t)r * K + k0 + scol, &Bsm[buf][ch * 16][0]);
        }
    };

    auto compute = [&](int buf) {
        s16x8 af[4], bf[NN];
#pragma unroll
        for (int i = 0; i < 4; ++i)
            af[i] = *reinterpret_cast<const s16x8*>(&Asm[buf][wr * 64 + i * 16 + c][g * 8]);
#pragma unroll
        for (int n = 0; n < NN; ++n)
            bf[n] = *reinterpret_cast<const s16x8*>(&Bsm[buf][wc * (BN / 2) + n * 16 + c][g * 8]);
#pragma unroll
        for (int i = 0; i < 4; ++i)
#pragma unroll
            for (int n = 0; n < NN; ++n)
                acc[i][n] = __builtin_amdgcn_mfma_f32_16x16x32_bf16(af[i], bf[n], acc[i][n], 0, 0, 0);
    };

    const int NK = K >> 5;
    stage(0, 0);
    stage(1, 32);
    int buf = 0;
    for (int i = 0; i < NK - 1; ++i) {
        if constexpr (BCH == 2) asm volatile("s_waitcnt vmcnt(4)" ::: "memory");
        else                    asm volatile("s_waitcnt vmcnt(3)" ::: "memory");
        __builtin_amdgcn_s_barrier();
        compute(buf);
        if (i + 2 < NK) {
            int nb = buf + 2; if (nb >= 3) nb -= 3;
            stage(nb, (i + 2) << 5);
        }
        ++buf; if (buf == 3) buf = 0;
    }
    asm volatile("s_waitcnt vmcnt(0)" ::: "memory");
    __builtin_amdgcn_s_barrier();
    compute(buf);

    const int crow = g * 4;
#pragma unroll
    for (int i = 0; i < 4; ++i) {
#pragma unroll
        for (int n = 0; n < NN; ++n) {
            const int col = n0 + wc * (BN / 2) + n * 16 + c;
#pragma unroll
            for (int j = 0; j < 4; ++j) {
                const int row = m0 + wr * 64 + i * 16 + crow + j;
                float v = acc[i][n][j];
                if constexpr (EPI == 2) {
                    v = gelu_f(v + bias[col]);
                    ((unsigned short*)Cv)[(size_t)row * N + col] = f2bf(v);
                } else if constexpr (EPI == 3) {
                    v = v + bias[col] + resid[(size_t)row * N + col];
                    ((float*)Cv)[(size_t)row * N + col] = v;
                } else if constexpr (EPI == 1) {
                    v = v + resid[(size_t)row * N + col];
                    ((float*)Cv)[(size_t)row * N + col] = v;
                } else {  // EPI == 4
                    if (col < 2048) {
                        // Q pre-scaled by 0.125 * log2(e) so attn can use exp2 directly
                        float vv = (col < 1024) ? v * 0.18033688011112042f : v;
                        ((unsigned short*)Cv)[(size_t)row * LDK + col] = f2bf(vv);
                    } else {
                        ((unsigned short*)Cv2)[(size_t)(col - 2048) * T_TOK + row] = f2bf(v);
                    }
                }
            }
        }
    }
}

// ---------------- Flash attention (fixed-max softmax, swapped QK^T, 8 waves) ----------------
// grid: (S/128, H, B); 8 waves x 16 q rows = 128 q rows/block. KV tile = 64, double-buffered,
// single barrier per tile. p = exp2(s) (Q pre-scaled by 0.125*log2e in GEMM epilogue).
// 8 waves share each staged K/V tile (2x MFMA per staged byte vs 4-wave version).
__global__ __launch_bounds__(512) void attn_kernel(const unsigned short* __restrict__ QK,
                                                   const unsigned short* __restrict__ Vt,
                                                   const unsigned char* __restrict__ mask,
                                                   unsigned short* __restrict__ O) {
    const int qt = blockIdx.x, h = blockIdx.y, b = blockIdx.z;
    const int t = threadIdx.x, lane = t & 63, w = t >> 6;
    const int c = lane & 15, g = lane >> 4;
    const int crow = g * 4;
    const int qb0 = qt * 128;
    const int qw = qb0 + w * 16;
    const int swzc16 = swz(c) << 4;

    __shared__ unsigned short Ksm[2][64][64];    // [key][d], 16B-slot swizzled by key
    __shared__ unsigned short Vsm[2][64][64];    // [d][key], 16B-slot swizzled by d
    __shared__ unsigned short Psm[8][16][64];    // per-wave P[q][key], swizzled by q
    __shared__ unsigned char Msm[128][64];

    // Q fragment (pre-scaled): lane (g,c) holds Q[qw+c][d = kh*32 + g*8 + e]
    s16x8 qf[2];
    {
        const unsigned short* qp = QK + (size_t)(b * S_LEN + qw + c) * LDK + h * 64 + g * 8;
        qf[0] = *reinterpret_cast<const s16x8*>(qp);
        qf[1] = *reinterpret_cast<const s16x8*>(qp + 32);
    }

    float lsum = 0.f;
    f32x4 oacc[4] = {};

    const int vtok = t >> 2;            // 0..127 (mask q-row within block)
    const int vd0 = (t & 3) * 16;
    const unsigned char* mcol = mask + (size_t)b * S_LEN * S_LEN + (size_t)(qb0 + vtok) * S_LEN + vd0;
    const unsigned short* kg = QK + 1024;
    const int srow8 = lane >> 3, sslot = lane & 7;

    // each wave stages 8 rows of K and 8 d-rows of V^T (1 gload each per thread)
    auto stage = [&](int buf, int kt) {
        int r = w * 8 + srow8;
        int slot = sslot ^ swz(r);
        gload_lds16(kg + (size_t)(b * S_LEN + kt + r) * LDK + h * 64 + slot * 8,
                    &Ksm[buf][w * 8][0]);
        gload_lds16(Vt + (size_t)(h * 64 + r) * T_TOK + b * S_LEN + kt + slot * 8,
                    &Vsm[buf][w * 8][0]);
    };

    // prologue: stage tile 0, aggregate its mask
    stage(0, 0);
    uint4 mv0 = *reinterpret_cast<const uint4*>(mcol);
    asm volatile("s_waitcnt vmcnt(0)" ::: "memory");
    int anym = __syncthreads_or((mv0.x | mv0.y | mv0.z | mv0.w) != 0);
    if (anym) {
        *reinterpret_cast<uint4*>(&Msm[vtok][vd0]) = mv0;
        __syncthreads();
    }

    constexpr int NT = S_LEN / 64;
    for (int it = 0; it < NT; ++it) {
        const int cur = it & 1;
        uint4 mv = {0u, 0u, 0u, 0u};
        if (it < NT - 1) {
            stage(cur ^ 1, (it + 1) * 64);
            mv = *reinterpret_cast<const uint4*>(mcol + (it + 1) * 64);
        }

        // --- S^T = K·Q^T : lane (g,c) gets S[q = qw+c][key = kb*16 + g*4 + j]
        f32x4 s[4] = {};
#pragma unroll
        for (int kh = 0; kh < 2; ++kh) {
#pragma unroll
            for (int kb = 0; kb < 4; ++kb) {
                int key = kb * 16 + c;
                int byte = key * 128 + (((kh * 4 + g) ^ swz(key)) << 4);
                s16x8 kf = *(const s16x8*)((const char*)&Ksm[cur][0][0] + byte);
                s[kb] = __builtin_amdgcn_mfma_f32_16x16x32_bf16(kf, qf[kh], s[kb], 0, 0, 0);
            }
        }
        if (anym) {
#pragma unroll
            for (int kb = 0; kb < 4; ++kb)
#pragma unroll
                for (int j = 0; j < 4; ++j)
                    if (Msm[w * 16 + c][kb * 16 + crow + j]) s[kb][j] = -1e9f;
        }

        // --- p = exp2(s) (scale folded into Q); pack; write P[q=c][key] (b64, swizzled by q)
#pragma unroll
        for (int kb = 0; kb < 4; ++kb) {
            float p0 = exp2f(s[kb][0]);
            float p1 = exp2f(s[kb][1]);
            float p2 = exp2f(s[kb][2]);
            float p3 = exp2f(s[kb][3]);
            lsum += (p0 + p1) + (p2 + p3);
            uint2 pk = make_uint2(pack_bf2(p0, p1), pack_bf2(p2, p3));
            int byte = c * 128 + ((kb * 32 + g * 8) ^ swzc16);
            *(uint2*)((char*)&Psm[w][0][0] + byte) = pk;
        }

        // --- PV: O[q][d] += P[q][key] V[key][d]
#pragma unroll
        for (int kh = 0; kh < 2; ++kh) {
            int pbyte = c * 128 + ((kh * 64 + g * 16) ^ swzc16);
            s16x8 pf = *(const s16x8*)((const char*)&Psm[w][0][0] + pbyte);
#pragma unroll
            for (int nb = 0; nb < 4; ++nb) {
                int d = nb * 16 + c;
                int byte = d * 128 + (((kh * 4 + g) ^ swz(d)) << 4);
                s16x8 vf = *(const s16x8*)((const char*)&Vsm[cur][0][0] + byte);
                oacc[nb] = __builtin_amdgcn_mfma_f32_16x16x32_bf16(pf, vf, oacc[nb], 0, 0, 0);
            }
        }

        // --- drain prefetch, single barrier (doubles as next-tile mask aggregation)
        asm volatile("s_waitcnt vmcnt(0)" ::: "memory");
        int nxt = __syncthreads_or((mv.x | mv.y | mv.z | mv.w) != 0);
        if (nxt) {
            *reinterpret_cast<uint4*>(&Msm[vtok][vd0]) = mv;
            __syncthreads();
        }
        anym = nxt;
    }

    // --- finish l: reduce partials across g-groups, broadcast per output row
    lsum += __shfl_xor(lsum, 16);
    lsum += __shfl_xor(lsum, 32);
    float inv[4];
#pragma unroll
    for (int j = 0; j < 4; ++j) {
        float lq = __shfl(lsum, crow + j);
        inv[j] = lq > 0.f ? 1.0f / lq : 0.f;
    }
#pragma unroll
    for (int nb = 0; nb < 4; ++nb) {
#pragma unroll
        for (int j = 0; j < 4; ++j) {
            const size_t oo = (size_t)(b * S_LEN + qw + crow + j) * DM + h * 64 + nb * 16 + c;
            O[oo] = f2bf(oacc[nb][j] * inv[j]);
        }
    }
}

// ---------------- launch ----------------
extern "C" void kernel_launch(void* const* d_in, const int* in_sizes, int n_in,
                              void* d_out, int out_size, void* d_ws, size_t ws_size,
                              hipStream_t stream) {
    (void)in_sizes; (void)n_in; (void)out_size; (void)ws_size;
    const float* x   = (const float*)d_in[0];
    const unsigned char* mask = (const unsigned char*)d_in[1];
    const float* WQ  = (const float*)d_in[2];
    const float* WK  = (const float*)d_in[3];
    const float* WV  = (const float*)d_in[4];
    const float* WO  = (const float*)d_in[5];
    const float* F1W = (const float*)d_in[6];
    const float* F1B = (const float*)d_in[7];
    const float* F2W = (const float*)d_in[8];
    const float* F2B = (const float*)d_in[9];
    const float* L1G = (const float*)d_in[10];
    const float* L1B = (const float*)d_in[11];
    const float* L2G = (const float*)d_in[12];
    const float* L2B = (const float*)d_in[13];
    float* out = (float*)d_out;

    char* ws = (char*)d_ws;
    size_t off = 0;
    auto alloc = [&](size_t bytes) -> void* {
        void* p = ws + off;
        off += (bytes + 255) & ~(size_t)255;
        return p;
    };
    unsigned short* h1    = (unsigned short*)alloc((size_t)T_TOK * DM * 2);
    unsigned short* qk    = (unsigned short*)alloc((size_t)T_TOK * LDK * 2);
    unsigned short* vt    = (unsigned short*)alloc((size_t)DM * T_TOK * 2);
    unsigned short* ctx   = (unsigned short*)alloc((size_t)T_TOK * DM * 2);
    float*          x2    = (float*)alloc((size_t)T_TOK * DM * 4);
    unsigned short* h2    = (unsigned short*)alloc((size_t)T_TOK * DM * 2);
    unsigned short* h3    = (unsigned short*)alloc((size_t)T_TOK * DFF * 2);
    unsigned short* WQKVt = (unsigned short*)alloc((size_t)3 * DM * DM * 2);
    unsigned short* WOt   = (unsigned short*)alloc((size_t)DM * DM * 2);
    unsigned short* F1Wt  = (unsigned short*)alloc((size_t)DFF * DM * 2);
    unsigned short* F2Wt  = (unsigned short*)alloc((size_t)DM * DFF * 2);

    dim3 t32(DM / 32, DM / 32);
    tcvt_kernel<<<t32, 256, 0, stream>>>(WQ, WQKVt, DM, DM);
    tcvt_kernel<<<t32, 256, 0, stream>>>(WK, WQKVt + (size_t)DM * DM, DM, DM);
    tcvt_kernel<<<t32, 256, 0, stream>>>(WV, WQKVt + (size_t)2 * DM * DM, DM, DM);
    tcvt_kernel<<<t32, 256, 0, stream>>>(WO, WOt, DM, DM);
    tcvt_kernel<<<dim3(DFF / 32, DM / 32), 256, 0, stream>>>(F1W, F1Wt, DM, DFF);
    tcvt_kernel<<<dim3(DM / 32, DFF / 32), 256, 0, stream>>>(F2W, F2Wt, DFF, DM);

    ln_kernel<<<T_TOK, 256, 0, stream>>>(x, L1G, L1B, h1);

    gemm_kernel<4, 128><<<dim3(3072 / 128, T_TOK / 128), 256, 0, stream>>>(
        h1, WQKVt, nullptr, nullptr, qk, vt, T_TOK, 3072, DM);

    attn_kernel<<<dim3(S_LEN / 128, 16, NB), 512, 0, stream>>>(qk, vt, mask, ctx);

    gemm_kernel<1, 64><<<dim3(DM / 64, T_TOK / 128), 256, 0, stream>>>(
        ctx, WOt, nullptr, x, x2, nullptr, T_TOK, DM, DM);

    ln_kernel<<<T_TOK, 256, 0, stream>>>(x2, L2G, L2B, h2);

    gemm_kernel<2, 128><<<dim3(DFF / 128, T_TOK / 128), 256, 0, stream>>>(
        h2, F1Wt, F1B, nullptr, h3, nullptr, T_TOK, DFF, DM);

    gemm_kernel<3, 128><<<dim3(DM / 128, T_TOK / 128), 256, 0, stream>>>(
        h3, F2Wt, F2B, x2, out, nullptr, T_TOK, DM, DFF);
}